// Round 1
// 215.785 us; speedup vs baseline: 1.0407x; 1.0407x over previous
//
#include <hip/hip_runtime.h>
#include <hip/hip_bf16.h>

using bf16 = __hip_bfloat16;
typedef __bf16 bf16x8 __attribute__((ext_vector_type(8)));
typedef __bf16 bf16x2v __attribute__((ext_vector_type(2)));
typedef float f32x4 __attribute__((ext_vector_type(4)));

#define SEQ 2048
#define DM  1024
// 0.125 * log2(e): folded into Q so scores come out of MFMA in log2 domain.
#define QSCALE 0.18033688011112042f

__device__ __forceinline__ f32x4 mfma16(bf16x8 a, bf16x8 b, f32x4 c) {
  return __builtin_amdgcn_mfma_f32_16x16x32_bf16(a, b, c, 0, 0, 0);
}
__device__ __forceinline__ void gload16(const void* g, void* l) {
  __builtin_amdgcn_global_load_lds(
      (const __attribute__((address_space(1))) unsigned int*)g,
      (__attribute__((address_space(3))) unsigned int*)l, 16, 0, 0);
}
__device__ __forceinline__ unsigned short bfbits(float x) {
  bf16 h = __float2bfloat16(x);
  return *reinterpret_cast<unsigned short*>(&h);
}
// Pack two fp32 -> bf16x2 (RNE). Single v_cvt_pk_bf16_f32 on gfx950 if the
// builtin exists; otherwise the portable RNE path.
__device__ __forceinline__ unsigned pk2(float a, float b) {
#if __has_builtin(__builtin_amdgcn_cvt_pk_bf16_f32)
  bf16x2v r = __builtin_amdgcn_cvt_pk_bf16_f32(a, b);
  return *reinterpret_cast<unsigned*>(&r);
#else
  return (unsigned)bfbits(a) | ((unsigned)bfbits(b) << 16);
#endif
}
// Bare v_exp_f32 (2^x) without libm guards.
__device__ __forceinline__ float fexp2(float x) {
#if __has_builtin(__builtin_amdgcn_exp2f)
  return __builtin_amdgcn_exp2f(x);
#else
  return exp2f(x);
#endif
}

// ---------------- Pass A: X fp32 [4096][1024] -> frag-tiled bf16 ----------------
// Layout Lx: [input 3][s16 256][k32 32][lane 64][8 elems]. lane l: seq=s16*16+(l&15),
// d = k32*32 + (l>>4)*8 .. +7.
__global__ __launch_bounds__(256) void cast_x(const float* __restrict__ q,
                                              const float* __restrict__ k,
                                              const float* __restrict__ v,
                                              bf16* __restrict__ Lx) {
  const float* src = blockIdx.y == 0 ? q : (blockIdx.y == 1 ? k : v);
  bf16* dst = Lx + (size_t)blockIdx.y * (4096ull * 1024) + (size_t)blockIdx.x * 16384;
#pragma unroll
  for (int i = 0; i < 8; ++i) {
    int u = threadIdx.x + i * 256;
    int k32 = u >> 6, l = u & 63;
    const float* p = src + (size_t)(blockIdx.x * 16 + (l & 15)) * 1024 + k32 * 32 + (l >> 4) * 8;
    float4 a = *(const float4*)p;
    float4 b = *(const float4*)(p + 4);
    alignas(16) unsigned o[4] = {pk2(a.x, a.y), pk2(a.z, a.w), pk2(b.x, b.y), pk2(b.z, b.w)};
    *(uint4*)(dst + (size_t)u * 8) = *(const uint4*)o;
  }
}

// ---------------- Pass B: W fp32 [k][n] -> W^T frag-tiled bf16 ----------------
__global__ __launch_bounds__(256) void cast_w(const float* __restrict__ Wq,
                                              const float* __restrict__ Wk,
                                              const float* __restrict__ Wv,
                                              const float* __restrict__ Wo,
                                              bf16* __restrict__ Lw,
                                              bf16* __restrict__ Lwo) {
  const int widx = blockIdx.z;
  const float* W = widx == 0 ? Wq : (widx == 1 ? Wk : (widx == 2 ? Wv : Wo));
  bf16* dst = widx < 3 ? (Lw + (size_t)widx * 1048576) : Lwo;
  __shared__ float tf[64][68];
  const int t = threadIdx.x, bx = blockIdx.x, by = blockIdx.y;
#pragma unroll
  for (int i = 0; i < 4; ++i) {
    int u = t + i * 256, r = u >> 4, c4 = u & 15;
    *(float4*)&tf[r][c4 * 4] = *(const float4*)(W + (size_t)(by * 64 + r) * 1024 + bx * 64 + c4 * 4);
  }
  __syncthreads();
#pragma unroll
  for (int i = 0; i < 2; ++i) {
    int u = t + i * 256;
    int sub = u >> 6, l = u & 63;
    int n16l = sub >> 1, k32l = sub & 1;
    int nn = n16l * 16 + (l & 15);
    int kk = k32l * 32 + (l >> 4) * 8;
    alignas(16) unsigned o[4];
#pragma unroll
    for (int p = 0; p < 4; ++p) o[p] = pk2(tf[kk + 2 * p][nn], tf[kk + 2 * p + 1][nn]);
    size_t off = ((((size_t)(bx * 4 + n16l)) * 32 + (by * 2 + k32l)) * 64 + l) * 8;
    *(uint4*)(dst + off) = *(const uint4*)o;
  }
}

// ---------------- Fused QKV GEMM ----------------
// thirds 0/1 (Q/K): D[m=dout][n=seq] = W^T x X -> Lqk frag-tiled (lane=seq, holds d)
//   third 0 additionally scales by QSCALE (softmax fold).
// third 2 (V):      D[m=seq][n=dout] = X x W^T -> Lv frag-tiled V^T (lane=d, holds keys)
__global__ __launch_bounds__(256) void qkv_gemm(const bf16* __restrict__ Lw,
                                                const bf16* __restrict__ Lx,
                                                const float* __restrict__ bq,
                                                const float* __restrict__ bk,
                                                const float* __restrict__ bv,
                                                bf16* __restrict__ Lq,
                                                bf16* __restrict__ Lk,
                                                bf16* __restrict__ Lv) {
  __shared__ alignas(16) bf16 Wl[8192];
  __shared__ alignas(16) bf16 Xl[8192];
  const int t = threadIdx.x, lane = t & 63, w = t >> 6;
  const int m16 = lane & 15, g4 = lane >> 4;
  const int third = blockIdx.y >> 3, mtl = blockIdx.y & 7, nt = blockIdx.x;
  const int wm = w >> 1, wn = w & 1;
  const bf16* Wb = Lw + (size_t)third * 1048576;
  const bf16* Xb = Lx + (size_t)third * (4096ull * 1024);
  f32x4 acc[4][4] = {};

  for (int slab = 0; slab < 16; ++slab) {
#pragma unroll
    for (int ii = 0; ii < 4; ++ii) {
      int s = w * 4 + ii;
      const bf16* gp = Wb + ((((size_t)(mtl * 8 + (s >> 1))) * 32 + slab * 2 + (s & 1)) * 64 + lane) * 8;
      gload16(gp, (void*)&Wl[s * 512]);
    }
#pragma unroll
    for (int ii = 0; ii < 4; ++ii) {
      int s = w * 4 + ii;
      const bf16* gp = Xb + ((((size_t)(nt * 8 + (s >> 1))) * 32 + slab * 2 + (s & 1)) * 64 + lane) * 8;
      gload16(gp, (void*)&Xl[s * 512]);
    }
    __syncthreads();
#pragma unroll
    for (int c = 0; c < 2; ++c) {
      bf16x8 wf[4], xf[4];
#pragma unroll
      for (int i = 0; i < 4; ++i) wf[i] = *(const bf16x8*)&Wl[((wm * 4 + i) * 2 + c) * 512 + lane * 8];
#pragma unroll
      for (int j = 0; j < 4; ++j) xf[j] = *(const bf16x8*)&Xl[((wn * 4 + j) * 2 + c) * 512 + lane * 8];
      if (third < 2) {
#pragma unroll
        for (int i = 0; i < 4; ++i)
#pragma unroll
          for (int j = 0; j < 4; ++j) acc[i][j] = mfma16(wf[i], xf[j], acc[i][j]);
      } else {
#pragma unroll
        for (int i = 0; i < 4; ++i)
#pragma unroll
          for (int j = 0; j < 4; ++j) acc[i][j] = mfma16(xf[i], wf[j], acc[i][j]);
      }
    }
    __syncthreads();
  }

  if (third < 2) {
    bf16* dst = third == 0 ? Lq : Lk;
    const float* bias = third == 0 ? bq : bk;
    const float sc = third == 0 ? QSCALE : 1.0f;
#pragma unroll
    for (int i = 0; i < 4; ++i) {
      int doutb = mtl * 128 + wm * 64 + i * 16 + g4 * 4;
      float4 b4 = *(const float4*)(bias + doutb);
      int hh = doutb >> 6, d32 = (doutb & 63) >> 5;
      int lhi = (doutb & 31) >> 3, half = g4 & 1;
#pragma unroll
      for (int j = 0; j < 4; ++j) {
        int seq = nt * 128 + wn * 64 + j * 16 + m16;
        int bb = seq >> 11, s16w = (seq & 2047) >> 4;
        size_t off = ((((size_t)(bb * 128 + s16w)) * 16 + hh) * 2 + d32) * 512 + (m16 + 16 * lhi) * 8 + half * 4;
        uint2 pv;
        pv.x = pk2((acc[i][j][0] + b4.x) * sc, (acc[i][j][1] + b4.y) * sc);
        pv.y = pk2((acc[i][j][2] + b4.z) * sc, (acc[i][j][3] + b4.w) * sc);
        *(uint2*)(dst + off) = pv;
      }
    }
  } else {
#pragma unroll
    for (int j = 0; j < 4; ++j) {
      int dout = mtl * 128 + wm * 64 + j * 16 + m16;
      float bvv = bv[dout];
      int hh = dout >> 6, dt = (dout & 63) >> 4;
#pragma unroll
      for (int i = 0; i < 4; ++i) {
        int seqb = nt * 128 + wn * 64 + i * 16 + g4 * 4;
        int bb = seqb >> 11, kt = (seqb & 2047) >> 6, ks32 = (seqb & 63) >> 5;
        int lhi = (seqb & 31) >> 3, half = g4 & 1;
        size_t off = (((((size_t)(bb * 32 + kt)) * 16 + hh) * 4 + dt) * 2 + ks32) * 512 + (m16 + 16 * lhi) * 8 + half * 4;
        uint2 pv;
        pv.x = pk2(acc[i][j][0] + bvv, acc[i][j][1] + bvv);
        pv.y = pk2(acc[i][j][2] + bvv, acc[i][j][3] + bvv);
        *(uint2*)(Lv + off) = pv;
      }
    }
  }
}

// ---------------- Flash attention, in-block key-split ----------------
// 512 threads = 8 waves. Warp w (group g=w>>2) processes queries (w&3)*32..+31 of
// the 128-q tile against key half g (1024 keys, 32 kt-steps of 32 keys).
// m == 0 constant softmax => split-K combine is a pure sum of (O, l).
// Per-group double-buffered K/V tiles; per-warp P^T LDS scratch [32][36]
// (stride 36 keeps uint2 writes 8B-aligned and spreads banks ~2-way).
__global__ __launch_bounds__(512, 4) void flash(const bf16* __restrict__ Lq,
                                                const bf16* __restrict__ Lk,
                                                const bf16* __restrict__ Lv,
                                                bf16* __restrict__ Lab) {
  // [0,16384)  K tiles: [grp 2][buf 2][2048 bf16]
  // [16384,32768) V tiles: same shape
  // [32768,51200) Pt: [8 warps][32][36] bf16
  // after loop: [0,32768) O-partial f32 scratch, [32768,33280) l f32 scratch
  __shared__ alignas(16) unsigned char smem[51200];
  bf16* const Kb = (bf16*)smem;
  bf16* const Vb = (bf16*)(smem + 16384);
  bf16* const Pt = (bf16*)(smem + 32768);

  const int t = threadIdx.x, lane = t & 63, w = t >> 6;
  const int m16 = lane & 15, g4 = lane >> 4;
  const int wg = w & 3, g = w >> 2;
  // XCD swizzle: grid=512 (%8==0), group the 16 q-tiles of one head on one XCD.
  const int bid = blockIdx.x;
  const int logical = ((bid & 7) << 6) | (bid >> 3);
  const int qt = logical & 15, h = (logical >> 4) & 15, b = logical >> 8;

  bf16* const Ptw = Pt + w * (32 * 36);

  // Q fragments straight from global (frag layout -> coalesced)
  bf16x8 qf[2][2];
#pragma unroll
  for (int q2 = 0; q2 < 2; ++q2)
#pragma unroll
    for (int ks = 0; ks < 2; ++ks)
      qf[q2][ks] = *(const bf16x8*)(Lq +
          ((((size_t)(b * 128 + qt * 8 + wg * 2 + q2)) * 16 + h) * 2 + ks) * 512 + lane * 8);

  // stage tile 0 of this group's key half: each warp 1 K chunk + 1 V chunk
  const int s16l = wg >> 1, d32 = wg & 1;
  {
    const bf16* gk = Lk + ((((size_t)(b * 128 + g * 64 + s16l)) * 16 + h) * 2 + d32) * 512 + lane * 8;
    gload16(gk, (void*)(Kb + (g * 2 + 0) * 2048 + wg * 512));
    const bf16* gv = Lv + (((((size_t)(b * 32 + g * 16)) * 16 + h) * 4 + wg) * 2 + 0) * 512 + lane * 8;
    gload16(gv, (void*)(Vb + (g * 2 + 0) * 2048 + wg * 512));
  }

  float lrow[2] = {0.f, 0.f};
  f32x4 oacc[4][2] = {};
  __syncthreads();

  for (int kt = 0; kt < 32; ++kt) {
    const int cur = kt & 1;
    const bf16* const Kl = Kb + (g * 2 + cur) * 2048;
    const bf16* const Vl = Vb + (g * 2 + cur) * 2048;
    if (kt < 31) {
      const int nkt = kt + 1, nb = cur ^ 1;
      const bf16* gk = Lk + ((((size_t)(b * 128 + g * 64 + nkt * 2 + s16l)) * 16 + h) * 2 + d32) * 512 + lane * 8;
      gload16(gk, (void*)(Kb + (g * 2 + nb) * 2048 + wg * 512));
      const bf16* gv = Lv + (((((size_t)(b * 32 + g * 16 + (nkt >> 1))) * 16 + h) * 4 + wg) * 2 + (nkt & 1)) * 512 + lane * 8;
      gload16(gv, (void*)(Vb + (g * 2 + nb) * 2048 + wg * 512));
    }

    // S^T[key 32][q 32] in log2 domain (Q pre-scaled by 0.125*log2e)
    f32x4 s[2][2] = {};
#pragma unroll
    for (int ks = 0; ks < 2; ++ks) {
      bf16x8 aK[2];
#pragma unroll
      for (int mt = 0; mt < 2; ++mt) aK[mt] = *(const bf16x8*)&Kl[(mt * 2 + ks) * 512 + lane * 8];
#pragma unroll
      for (int mt = 0; mt < 2; ++mt)
#pragma unroll
        for (int q2 = 0; q2 < 2; ++q2) s[mt][q2] = mfma16(aK[mt], qf[q2][ks], s[mt][q2]);
    }

    // P = exp2(S'), accumulate l per-lane, pack+write P^T tile (wave-private)
#pragma unroll
    for (int q2 = 0; q2 < 2; ++q2)
#pragma unroll
      for (int mt = 0; mt < 2; ++mt) {
        float e0 = fexp2(s[mt][q2][0]);
        float e1 = fexp2(s[mt][q2][1]);
        float e2 = fexp2(s[mt][q2][2]);
        float e3 = fexp2(s[mt][q2][3]);
        lrow[q2] += (e0 + e1) + (e2 + e3);
        uint2 pv;
        pv.x = pk2(e0, e1);
        pv.y = pk2(e2, e3);
        *(uint2*)&Ptw[(q2 * 16 + m16) * 36 + mt * 16 + g4 * 4] = pv;
      }

    // O^T += V^T P^T  (Pt rows wave-private; lgkmcnt orders write->read)
    {
      bf16x8 aV[4], bP[2];
#pragma unroll
      for (int dt = 0; dt < 4; ++dt) aV[dt] = *(const bf16x8*)&Vl[dt * 512 + lane * 8];
#pragma unroll
      for (int q2 = 0; q2 < 2; ++q2) {
        alignas(16) unsigned tmp[4];
        *(uint2*)&tmp[0] = *(const uint2*)&Ptw[(q2 * 16 + m16) * 36 + g4 * 8];
        *(uint2*)&tmp[2] = *(const uint2*)&Ptw[(q2 * 16 + m16) * 36 + g4 * 8 + 4];
        bP[q2] = *(const bf16x8*)tmp;
      }
#pragma unroll
      for (int dt = 0; dt < 4; ++dt)
#pragma unroll
        for (int q2 = 0; q2 < 2; ++q2) oacc[dt][q2] = mfma16(aV[dt], bP[q2], oacc[dt][q2]);
    }
    __syncthreads();
  }

  // reduce l across the 4 lane-groups sharing each q
#pragma unroll
  for (int q2 = 0; q2 < 2; ++q2) {
    lrow[q2] += __shfl_xor(lrow[q2], 16);
    lrow[q2] += __shfl_xor(lrow[q2], 32);
  }

  // combine the two key halves through LDS (K/V buffers are dead now)
  float* const Os = (float*)smem;            // [wg 4][dt 4][q2 2][lane 64][4]
  float* const Ls = (float*)(smem + 32768);  // [wg 4][q2 2][16]
  if (w >= 4) {
#pragma unroll
    for (int dt = 0; dt < 4; ++dt)
#pragma unroll
      for (int q2 = 0; q2 < 2; ++q2)
        *(f32x4*)&Os[(((wg * 4 + dt) * 2 + q2) * 64 + lane) * 4] = oacc[dt][q2];
    if (g4 == 0) {
      Ls[(wg * 2 + 0) * 16 + m16] = lrow[0];
      Ls[(wg * 2 + 1) * 16 + m16] = lrow[1];
    }
  }
  __syncthreads();
  if (w < 4) {
#pragma unroll
    for (int q2 = 0; q2 < 2; ++q2) {
      float inv = 1.f / (lrow[q2] + Ls[(wg * 2 + q2) * 16 + m16]);
      int q = b * 2048 + qt * 128 + w * 32 + q2 * 16 + m16;
      int s16g = q >> 4;
#pragma unroll
      for (int dt = 0; dt < 4; ++dt) {
        f32x4 p = *(const f32x4*)&Os[(((wg * 4 + dt) * 2 + q2) * 64 + lane) * 4];
        int dbase = h * 64 + dt * 16 + g4 * 4;
        int k32 = dbase >> 5, lhi = (dbase & 31) >> 3, half = g4 & 1;
        size_t off = ((size_t)s16g * 32 + k32) * 512 + (m16 + 16 * lhi) * 8 + half * 4;
        uint2 pv;
        pv.x = pk2((oacc[dt][q2][0] + p[0]) * inv, (oacc[dt][q2][1] + p[1]) * inv);
        pv.y = pk2((oacc[dt][q2][2] + p[2]) * inv, (oacc[dt][q2][3] + p[3]) * inv);
        *(uint2*)(Lab + off) = pv;
      }
    }
  }
}

// ---------------- Final GEMM: out[seq][n] = A @ Wo + bo (fp32 out) ----------------
__global__ __launch_bounds__(256) void out_gemm(const bf16* __restrict__ Lab,
                                                const bf16* __restrict__ Lwo,
                                                const float* __restrict__ bo,
                                                float* __restrict__ out) {
  __shared__ alignas(16) bf16 Al[8192];
  __shared__ alignas(16) bf16 Bl[4096];
  const int t = threadIdx.x, lane = t & 63, w = t >> 6;
  const int m16 = lane & 15, g4 = lane >> 4;
  const int nt = blockIdx.x, mt = blockIdx.y;
  const int wm = w >> 1, wn = w & 1;
  f32x4 acc[4][2] = {};

  for (int slab = 0; slab < 16; ++slab) {
#pragma unroll
    for (int ii = 0; ii < 4; ++ii) {
      int s = w * 4 + ii;
      const bf16* gp = Lab + (((size_t)(mt * 8 + (s >> 1))) * 32 + slab * 2 + (s & 1)) * 512 + lane * 8;
      gload16(gp, (void*)&Al[s * 512]);
    }
#pragma unroll
    for (int ii = 0; ii < 2; ++ii) {
      int s = w * 2 + ii;
      const bf16* gp = Lwo + (((size_t)(nt * 4 + (s >> 1))) * 32 + slab * 2 + (s & 1)) * 512 + lane * 8;
      gload16(gp, (void*)&Bl[s * 512]);
    }
    __syncthreads();
#pragma unroll
    for (int c = 0; c < 2; ++c) {
      bf16x8 aA[4], bW[2];
#pragma unroll
      for (int i = 0; i < 4; ++i) aA[i] = *(const bf16x8*)&Al[((wm * 4 + i) * 2 + c) * 512 + lane * 8];
#pragma unroll
      for (int j = 0; j < 2; ++j) bW[j] = *(const bf16x8*)&Bl[((wn * 2 + j) * 2 + c) * 512 + lane * 8];
#pragma unroll
      for (int i = 0; i < 4; ++i)
#pragma unroll
        for (int j = 0; j < 2; ++j) acc[i][j] = mfma16(aA[i], bW[j], acc[i][j]);
    }
    __syncthreads();
  }
#pragma unroll
  for (int j = 0; j < 2; ++j) {
    int n = nt * 64 + wn * 32 + j * 16 + m16;
    float bb = bo[n];
#pragma unroll
    for (int i = 0; i < 4; ++i) {
      int seqb = mt * 128 + wm * 64 + i * 16 + g4 * 4;
#pragma unroll
      for (int r = 0; r < 4; ++r) out[(size_t)(seqb + r) * 1024 + n] = acc[i][j][r] + bb;
    }
  }
}

extern "C" void kernel_launch(void* const* d_in, const int* in_sizes, int n_in,
                              void* d_out, int out_size, void* d_ws, size_t ws_size,
                              hipStream_t stream) {
  const float* query = (const float*)d_in[0];
  const float* key   = (const float*)d_in[1];
  const float* value = (const float*)d_in[2];
  const float* Wq = (const float*)d_in[3];
  const float* bq = (const float*)d_in[4];
  const float* Wk = (const float*)d_in[5];
  const float* bk = (const float*)d_in[6];
  const float* Wv = (const float*)d_in[7];
  const float* bv = (const float*)d_in[8];
  const float* Wo = (const float*)d_in[9];
  const float* bo = (const float*)d_in[10];
  float* out = (float*)d_out;

  bf16* Lw  = (bf16*)d_ws;
  bf16* Lwo = Lw + 3ull * 1048576;
  bf16* Lx  = Lwo + 1048576;
  bf16* Lq  = Lx + 3ull * 4194304;
  bf16* Lk  = Lq + 4194304;
  bf16* Lv  = Lk + 4194304;
  bf16* Lab = Lv + 4194304;

  cast_x<<<dim3(256, 3), 256, 0, stream>>>(query, key, value, Lx);
  cast_w<<<dim3(16, 16, 4), 256, 0, stream>>>(Wq, Wk, Wv, Wo, Lw, Lwo);
  qkv_gemm<<<dim3(32, 24), 256, 0, stream>>>(Lw, Lx, bq, bk, bv, Lq, Lk, Lv);
  flash<<<512, 512, 0, stream>>>(Lq, Lk, Lv, Lab);
  out_gemm<<<dim3(16, 32), 256, 0, stream>>>(Lab, Lwo, bo, out);
}

// Round 2
// 215.171 us; speedup vs baseline: 1.0436x; 1.0029x over previous
//
#include <hip/hip_runtime.h>
#include <hip/hip_bf16.h>

using bf16 = __hip_bfloat16;
typedef __bf16 bf16x8 __attribute__((ext_vector_type(8)));
typedef __bf16 bf16x2v __attribute__((ext_vector_type(2)));
typedef float f32x4 __attribute__((ext_vector_type(4)));
typedef float f32x16 __attribute__((ext_vector_type(16)));

#define SEQ 2048
#define DM  1024
// 0.125 * log2(e): folded into Q so scores come out of MFMA in log2 domain.
#define QSCALE 0.18033688011112042f

__device__ __forceinline__ f32x4 mfma16(bf16x8 a, bf16x8 b, f32x4 c) {
  return __builtin_amdgcn_mfma_f32_16x16x32_bf16(a, b, c, 0, 0, 0);
}
__device__ __forceinline__ f32x16 mfma32(bf16x8 a, bf16x8 b, f32x16 c) {
  return __builtin_amdgcn_mfma_f32_32x32x16_bf16(a, b, c, 0, 0, 0);
}
__device__ __forceinline__ void gload16(const void* g, void* l) {
  __builtin_amdgcn_global_load_lds(
      (const __attribute__((address_space(1))) unsigned int*)g,
      (__attribute__((address_space(3))) unsigned int*)l, 16, 0, 0);
}
__device__ __forceinline__ unsigned short bfbits(float x) {
  bf16 h = __float2bfloat16(x);
  return *reinterpret_cast<unsigned short*>(&h);
}
__device__ __forceinline__ unsigned pk2(float a, float b) {
#if __has_builtin(__builtin_amdgcn_cvt_pk_bf16_f32)
  bf16x2v r = __builtin_amdgcn_cvt_pk_bf16_f32(a, b);
  return *reinterpret_cast<unsigned*>(&r);
#else
  return (unsigned)bfbits(a) | ((unsigned)bfbits(b) << 16);
#endif
}
__device__ __forceinline__ float fexp2(float x) {
#if __has_builtin(__builtin_amdgcn_exp2f)
  return __builtin_amdgcn_exp2f(x);
#else
  return exp2f(x);
#endif
}
// v_permlane32_swap_b32 a, b: a[l>=32] <- b[l-32]; b[l<32] <- a[l+32].
__device__ __forceinline__ void plswap(unsigned& a, unsigned& b) {
  asm("v_permlane32_swap_b32 %0, %1" : "+v"(a), "+v"(b));
}

// ---------------- Fused cast pass: X and W -> frag-tiled bf16 ----------------
// blockIdx.y < 3: X pass (input blockIdx.y); else W pass (widx = y-3).
__global__ __launch_bounds__(256) void cast_all(const float* __restrict__ q,
                                                const float* __restrict__ k,
                                                const float* __restrict__ v,
                                                const float* __restrict__ Wq,
                                                const float* __restrict__ Wk,
                                                const float* __restrict__ Wv,
                                                const float* __restrict__ Wo,
                                                bf16* __restrict__ Lx,
                                                bf16* __restrict__ Lw,
                                                bf16* __restrict__ Lwo) {
  __shared__ float tf[64][68];
  if (blockIdx.y < 3) {
    const float* src = blockIdx.y == 0 ? q : (blockIdx.y == 1 ? k : v);
    bf16* dst = Lx + (size_t)blockIdx.y * (4096ull * 1024) + (size_t)blockIdx.x * 16384;
#pragma unroll
    for (int i = 0; i < 8; ++i) {
      int u = threadIdx.x + i * 256;
      int k32 = u >> 6, l = u & 63;
      const float* p = src + (size_t)(blockIdx.x * 16 + (l & 15)) * 1024 + k32 * 32 + (l >> 4) * 8;
      float4 a = *(const float4*)p;
      float4 b = *(const float4*)(p + 4);
      alignas(16) unsigned o[4] = {pk2(a.x, a.y), pk2(a.z, a.w), pk2(b.x, b.y), pk2(b.z, b.w)};
      *(uint4*)(dst + (size_t)u * 8) = *(const uint4*)o;
    }
    return;
  }
  const int widx = blockIdx.y - 3;
  const float* W = widx == 0 ? Wq : (widx == 1 ? Wk : (widx == 2 ? Wv : Wo));
  bf16* dst = widx < 3 ? (Lw + (size_t)widx * 1048576) : Lwo;
  const int t = threadIdx.x, bx = blockIdx.x & 15, by = blockIdx.x >> 4;
#pragma unroll
  for (int i = 0; i < 4; ++i) {
    int u = t + i * 256, r = u >> 4, c4 = u & 15;
    *(float4*)&tf[r][c4 * 4] = *(const float4*)(W + (size_t)(by * 64 + r) * 1024 + bx * 64 + c4 * 4);
  }
  __syncthreads();
#pragma unroll
  for (int i = 0; i < 2; ++i) {
    int u = t + i * 256;
    int sub = u >> 6, l = u & 63;
    int n16l = sub >> 1, k32l = sub & 1;
    int nn = n16l * 16 + (l & 15);
    int kk = k32l * 32 + (l >> 4) * 8;
    alignas(16) unsigned o[4];
#pragma unroll
    for (int p = 0; p < 4; ++p) o[p] = pk2(tf[kk + 2 * p][nn], tf[kk + 2 * p + 1][nn]);
    size_t off = ((((size_t)(bx * 4 + n16l)) * 32 + (by * 2 + k32l)) * 64 + l) * 8;
    *(uint4*)(dst + off) = *(const uint4*)o;
  }
}

// ---------------- Fused QKV GEMM ----------------
__global__ __launch_bounds__(256) void qkv_gemm(const bf16* __restrict__ Lw,
                                                const bf16* __restrict__ Lx,
                                                const float* __restrict__ bq,
                                                const float* __restrict__ bk,
                                                const float* __restrict__ bv,
                                                bf16* __restrict__ Lq,
                                                bf16* __restrict__ Lk,
                                                bf16* __restrict__ Lv) {
  __shared__ alignas(16) bf16 Wl[8192];
  __shared__ alignas(16) bf16 Xl[8192];
  const int t = threadIdx.x, lane = t & 63, w = t >> 6;
  const int m16 = lane & 15, g4 = lane >> 4;
  const int third = blockIdx.y >> 3, mtl = blockIdx.y & 7, nt = blockIdx.x;
  const int wm = w >> 1, wn = w & 1;
  const bf16* Wb = Lw + (size_t)third * 1048576;
  const bf16* Xb = Lx + (size_t)third * (4096ull * 1024);
  f32x4 acc[4][4] = {};

  for (int slab = 0; slab < 16; ++slab) {
#pragma unroll
    for (int ii = 0; ii < 4; ++ii) {
      int s = w * 4 + ii;
      const bf16* gp = Wb + ((((size_t)(mtl * 8 + (s >> 1))) * 32 + slab * 2 + (s & 1)) * 64 + lane) * 8;
      gload16(gp, (void*)&Wl[s * 512]);
    }
#pragma unroll
    for (int ii = 0; ii < 4; ++ii) {
      int s = w * 4 + ii;
      const bf16* gp = Xb + ((((size_t)(nt * 8 + (s >> 1))) * 32 + slab * 2 + (s & 1)) * 64 + lane) * 8;
      gload16(gp, (void*)&Xl[s * 512]);
    }
    __syncthreads();
#pragma unroll
    for (int c = 0; c < 2; ++c) {
      bf16x8 wf[4], xf[4];
#pragma unroll
      for (int i = 0; i < 4; ++i) wf[i] = *(const bf16x8*)&Wl[((wm * 4 + i) * 2 + c) * 512 + lane * 8];
#pragma unroll
      for (int j = 0; j < 4; ++j) xf[j] = *(const bf16x8*)&Xl[((wn * 4 + j) * 2 + c) * 512 + lane * 8];
      if (third < 2) {
#pragma unroll
        for (int i = 0; i < 4; ++i)
#pragma unroll
          for (int j = 0; j < 4; ++j) acc[i][j] = mfma16(wf[i], xf[j], acc[i][j]);
      } else {
#pragma unroll
        for (int i = 0; i < 4; ++i)
#pragma unroll
          for (int j = 0; j < 4; ++j) acc[i][j] = mfma16(xf[i], wf[j], acc[i][j]);
      }
    }
    __syncthreads();
  }

  if (third < 2) {
    bf16* dst = third == 0 ? Lq : Lk;
    const float* bias = third == 0 ? bq : bk;
    const float sc = third == 0 ? QSCALE : 1.0f;
#pragma unroll
    for (int i = 0; i < 4; ++i) {
      int doutb = mtl * 128 + wm * 64 + i * 16 + g4 * 4;
      float4 b4 = *(const float4*)(bias + doutb);
      int hh = doutb >> 6, d32 = (doutb & 63) >> 5;
      int lhi = (doutb & 31) >> 3, half = g4 & 1;
#pragma unroll
      for (int j = 0; j < 4; ++j) {
        int seq = nt * 128 + wn * 64 + j * 16 + m16;
        int bb = seq >> 11, s16w = (seq & 2047) >> 4;
        size_t off = ((((size_t)(bb * 128 + s16w)) * 16 + hh) * 2 + d32) * 512 + (m16 + 16 * lhi) * 8 + half * 4;
        uint2 pv;
        pv.x = pk2((acc[i][j][0] + b4.x) * sc, (acc[i][j][1] + b4.y) * sc);
        pv.y = pk2((acc[i][j][2] + b4.z) * sc, (acc[i][j][3] + b4.w) * sc);
        *(uint2*)(dst + off) = pv;
      }
    }
  } else {
#pragma unroll
    for (int j = 0; j < 4; ++j) {
      int dout = mtl * 128 + wm * 64 + j * 16 + m16;
      float bvv = bv[dout];
      int hh = dout >> 6, dt = (dout & 63) >> 4;
#pragma unroll
      for (int i = 0; i < 4; ++i) {
        int seqb = nt * 128 + wn * 64 + i * 16 + g4 * 4;
        int bb = seqb >> 11, kt = (seqb & 2047) >> 6, ks32 = (seqb & 63) >> 5;
        int lhi = (seqb & 31) >> 3, half = g4 & 1;
        size_t off = (((((size_t)(bb * 32 + kt)) * 16 + hh) * 4 + dt) * 2 + ks32) * 512 + (m16 + 16 * lhi) * 8 + half * 4;
        uint2 pv;
        pv.x = pk2(acc[i][j][0] + bvv, acc[i][j][1] + bvv);
        pv.y = pk2(acc[i][j][2] + bvv, acc[i][j][3] + bvv);
        *(uint2*)(Lv + off) = pv;
      }
    }
  }
}

// ---------------- Flash attention: 32x32 MFMA, in-register P transpose ----------------
// 512 threads = 8 waves = 4 q-warps (32 q each) x 2 key-groups (1024 keys each).
// S^T = K Q^T via mfma_32x32x16 -> lane holds 16 scores of ONE q (col = lane&31).
// P->bf16 B-fragment built in-register: 4 cvt_pk + 2 permlane32_swap per 16-key slab.
// m == 0 constant softmax => key-split combine is a pure (O, l) sum through LDS.
// 64-key outer step (2 x 32-key sub-chunks) halves barrier count.
__global__ __launch_bounds__(512, 4) void flash(const bf16* __restrict__ Lq,
                                                const bf16* __restrict__ Lk,
                                                const bf16* __restrict__ Lv,
                                                bf16* __restrict__ Lab) {
  // [0,32768)     K tiles: [grp 2][buf 2][4096 bf16]
  // [32768,65536) V tiles: same shape
  // post-loop: [0,32768) O-partial f32 [8][16][64]; [32768,33280) l f32 [4][32]
  __shared__ alignas(16) unsigned char smem[65536];
  bf16* const Kb = (bf16*)smem;
  bf16* const Vb = (bf16*)(smem + 32768);

  const int t = threadIdx.x, lane = t & 63, w = t >> 6;
  const int l31 = lane & 31, m16 = lane & 15, hi = lane >> 5, b4 = (lane >> 4) & 1;
  const int qw = w >> 1, g = w & 1, wg = w >> 1;  // staging role == qw (unique in group)
  const int bid = blockIdx.x;
  const int logical = ((bid & 7) << 6) | (bid >> 3);
  const int qt = logical & 15, h = (logical >> 4) & 15, b = logical >> 8;

  // Q B-fragments: lane holds q = l31 (col), d = ks*16 + hi*8 + e
  bf16x8 qf[4];
  {
    const int sQ = b * 128 + qt * 8 + qw * 2 + b4;
#pragma unroll
    for (int ks = 0; ks < 4; ++ks) {
      const int d32 = ks >> 1, g4q = (ks & 1) * 2 + hi;
      qf[ks] = *(const bf16x8*)(Lq + (((size_t)sQ * 16 + h) * 2 + d32) * 512 + (m16 + 16 * g4q) * 8);
    }
  }

  // stage step 0 (64 keys = chunks 0,1 of this group's half)
  const int ss = wg >> 1, sd = wg & 1;
#pragma unroll
  for (int u = 0; u < 2; ++u) {
    const bf16* gk = Lk + ((((size_t)(b * 128 + g * 64 + u * 2 + ss)) * 16 + h) * 2 + sd) * 512 + lane * 8;
    gload16(gk, (void*)(Kb + (g * 2 + 0) * 4096 + u * 2048 + wg * 512));
    const bf16* gv = Lv + (((((size_t)(b * 32 + g * 16)) * 16 + h) * 4 + wg) * 2 + u) * 512 + lane * 8;
    gload16(gv, (void*)(Vb + (g * 2 + 0) * 4096 + u * 2048 + wg * 512));
  }

  float lrow = 0.f;
  f32x16 oacc[2] = {};
  __syncthreads();

  for (int it = 0; it < 16; ++it) {
    const int cur = it & 1;
    const bf16* const Klb = Kb + (g * 2 + cur) * 4096;
    const bf16* const Vlb = Vb + (g * 2 + cur) * 4096;
    if (it < 15) {
      const int nb = cur ^ 1;
#pragma unroll
      for (int u = 0; u < 2; ++u) {
        const int kc = (it + 1) * 2 + u;
        const bf16* gk = Lk + ((((size_t)(b * 128 + g * 64 + kc * 2 + ss)) * 16 + h) * 2 + sd) * 512 + lane * 8;
        gload16(gk, (void*)(Kb + (g * 2 + nb) * 4096 + u * 2048 + wg * 512));
        const bf16* gv = Lv + (((((size_t)(b * 32 + g * 16 + (kc >> 1))) * 16 + h) * 4 + wg) * 2 + (kc & 1)) * 512 + lane * 8;
        gload16(gv, (void*)(Vb + (g * 2 + nb) * 4096 + u * 2048 + wg * 512));
      }
    }

#pragma unroll
    for (int u = 0; u < 2; ++u) {
      const bf16* const Kl = Klb + u * 2048;
      const bf16* const Vl = Vlb + u * 2048;

      // S^T[key32][q32] over d=64: A = K-frag (row=key=l31, k=d), B = Q-frag
      f32x16 s = {};
      __builtin_amdgcn_s_setprio(1);
#pragma unroll
      for (int ks = 0; ks < 4; ++ks) {
        const int d32 = ks >> 1, g4k = (ks & 1) * 2 + hi;
        bf16x8 kf = *(const bf16x8*)&Kl[((b4 * 2 + d32) * 64 + m16 + 16 * g4k) * 8];
        s = mfma32(kf, qf[ks], s);
      }
      __builtin_amdgcn_s_setprio(0);

      // lane holds S'[q=l31][key = (r&3)+8*(r>>2)+4*hi] -> P = exp2, pack to B-frags
      float e[16];
#pragma unroll
      for (int r = 0; r < 16; ++r) e[r] = fexp2(s[r]);
      {
        float a0 = e[0] + e[1], a1 = e[2] + e[3], a2 = e[4] + e[5], a3 = e[6] + e[7];
        float a4 = e[8] + e[9], a5 = e[10] + e[11], a6 = e[12] + e[13], a7 = e[14] + e[15];
        lrow += ((a0 + a1) + (a2 + a3)) + ((a4 + a5) + (a6 + a7));
      }
      bf16x8 bP[2];
#pragma unroll
      for (int c = 0; c < 2; ++c) {
        unsigned P0 = pk2(e[8 * c + 0], e[8 * c + 1]);
        unsigned P1 = pk2(e[8 * c + 2], e[8 * c + 3]);
        unsigned P2 = pk2(e[8 * c + 4], e[8 * c + 5]);
        unsigned P3 = pk2(e[8 * c + 6], e[8 * c + 7]);
        plswap(P0, P2);  // -> word0 (keys 8hi+0,1), word2 (keys 8hi+4,5)
        plswap(P1, P3);  // -> word1 (keys 8hi+2,3), word3 (keys 8hi+6,7)
        alignas(16) unsigned pw[4] = {P0, P1, P2, P3};
        bP[c] = *(const bf16x8*)pw;
      }

      // O^T += V^T P^T : A = V^T-frag (row = d, k = key), B = P^T
      __builtin_amdgcn_s_setprio(1);
#pragma unroll
      for (int dtile = 0; dtile < 2; ++dtile) {
        const int dt = dtile * 2 + b4;
#pragma unroll
        for (int c = 0; c < 2; ++c) {
          bf16x8 av = *(const bf16x8*)&Vl[(dt * 64 + m16 + 16 * (2 * c + hi)) * 8];
          oacc[dtile] = mfma32(av, bP[c], oacc[dtile]);
        }
      }
      __builtin_amdgcn_s_setprio(0);
    }
    __syncthreads();
  }

  // per-q l: own 16 keys + complementary 16 in lane^32
  lrow += __shfl_xor(lrow, 32);

  // combine the two key halves through LDS (K/V buffers dead now)
  float* const Os = (float*)smem;              // [8][16][64]
  float* const Ls = (float*)(smem + 32768);    // [4][32]
  if (g == 1) {
#pragma unroll
    for (int dtile = 0; dtile < 2; ++dtile)
#pragma unroll
      for (int r = 0; r < 16; ++r)
        Os[((qw * 2 + dtile) * 16 + r) * 64 + lane] = oacc[dtile][r];
    if (hi == 0) Ls[qw * 32 + l31] = lrow;
  }
  __syncthreads();
  if (g == 0) {
    const float inv = 1.f / (lrow + Ls[qw * 32 + l31]);
    const int sQ = b * 128 + qt * 8 + qw * 2 + b4;
#pragma unroll
    for (int dtile = 0; dtile < 2; ++dtile) {
      const int k32 = h * 2 + dtile;
#pragma unroll
      for (int j = 0; j < 8; ++j) {
        const int r = 2 * j;
        float o0 = oacc[dtile][r] + Os[((qw * 2 + dtile) * 16 + r) * 64 + lane];
        float o1 = oacc[dtile][r + 1] + Os[((qw * 2 + dtile) * 16 + r + 1) * 64 + lane];
        unsigned pv = pk2(o0 * inv, o1 * inv);
        size_t off = ((size_t)sQ * 32 + k32) * 512 + (m16 + 16 * (r >> 2)) * 8 + 4 * hi + (r & 3);
        *(unsigned*)(Lab + off) = pv;
      }
    }
  }
}

// ---------------- Final GEMM: out[seq][n] = A @ Wo + bo (fp32 out) ----------------
__global__ __launch_bounds__(256) void out_gemm(const bf16* __restrict__ Lab,
                                                const bf16* __restrict__ Lwo,
                                                const float* __restrict__ bo,
                                                float* __restrict__ out) {
  __shared__ alignas(16) bf16 Al[8192];
  __shared__ alignas(16) bf16 Bl[4096];
  const int t = threadIdx.x, lane = t & 63, w = t >> 6;
  const int m16 = lane & 15, g4 = lane >> 4;
  const int nt = blockIdx.x, mt = blockIdx.y;
  const int wm = w >> 1, wn = w & 1;
  f32x4 acc[4][2] = {};

  for (int slab = 0; slab < 16; ++slab) {
#pragma unroll
    for (int ii = 0; ii < 4; ++ii) {
      int s = w * 4 + ii;
      const bf16* gp = Lab + (((size_t)(mt * 8 + (s >> 1))) * 32 + slab * 2 + (s & 1)) * 512 + lane * 8;
      gload16(gp, (void*)&Al[s * 512]);
    }
#pragma unroll
    for (int ii = 0; ii < 2; ++ii) {
      int s = w * 2 + ii;
      const bf16* gp = Lwo + (((size_t)(nt * 4 + (s >> 1))) * 32 + slab * 2 + (s & 1)) * 512 + lane * 8;
      gload16(gp, (void*)&Bl[s * 512]);
    }
    __syncthreads();
#pragma unroll
    for (int c = 0; c < 2; ++c) {
      bf16x8 aA[4], bW[2];
#pragma unroll
      for (int i = 0; i < 4; ++i) aA[i] = *(const bf16x8*)&Al[((wm * 4 + i) * 2 + c) * 512 + lane * 8];
#pragma unroll
      for (int j = 0; j < 2; ++j) bW[j] = *(const bf16x8*)&Bl[((wn * 2 + j) * 2 + c) * 512 + lane * 8];
#pragma unroll
      for (int i = 0; i < 4; ++i)
#pragma unroll
        for (int j = 0; j < 2; ++j) acc[i][j] = mfma16(aA[i], bW[j], acc[i][j]);
    }
    __syncthreads();
  }
#pragma unroll
  for (int j = 0; j < 2; ++j) {
    int n = nt * 64 + wn * 32 + j * 16 + m16;
    float bb = bo[n];
#pragma unroll
    for (int i = 0; i < 4; ++i) {
      int seqb = mt * 128 + wm * 64 + i * 16 + g4 * 4;
#pragma unroll
      for (int r = 0; r < 4; ++r) out[(size_t)(seqb + r) * 1024 + n] = acc[i][j][r] + bb;
    }
  }
}

extern "C" void kernel_launch(void* const* d_in, const int* in_sizes, int n_in,
                              void* d_out, int out_size, void* d_ws, size_t ws_size,
                              hipStream_t stream) {
  const float* query = (const float*)d_in[0];
  const float* key   = (const float*)d_in[1];
  const float* value = (const float*)d_in[2];
  const float* Wq = (const float*)d_in[3];
  const float* bq = (const float*)d_in[4];
  const float* Wk = (const float*)d_in[5];
  const float* bk = (const float*)d_in[6];
  const float* Wv = (const float*)d_in[7];
  const float* bv = (const float*)d_in[8];
  const float* Wo = (const float*)d_in[9];
  const float* bo = (const float*)d_in[10];
  float* out = (float*)d_out;

  bf16* Lw  = (bf16*)d_ws;
  bf16* Lwo = Lw + 3ull * 1048576;
  bf16* Lx  = Lwo + 1048576;
  bf16* Lq  = Lx + 3ull * 4194304;
  bf16* Lk  = Lq + 4194304;
  bf16* Lv  = Lk + 4194304;
  bf16* Lab = Lv + 4194304;

  cast_all<<<dim3(256, 7), 256, 0, stream>>>(query, key, value, Wq, Wk, Wv, Wo, Lx, Lw, Lwo);
  qkv_gemm<<<dim3(32, 24), 256, 0, stream>>>(Lw, Lx, bq, bk, bv, Lq, Lk, Lv);
  flash<<<512, 512, 0, stream>>>(Lq, Lk, Lv, Lab);
  out_gemm<<<dim3(16, 32), 256, 0, stream>>>(Lab, Lwo, bo, out);
}